// Round 18
// baseline (153.715 us; speedup 1.0000x reference)
//
#include <hip/hip_runtime.h>
#include <hip/hip_bf16.h>
#include <hip/hip_cooperative_groups.h>
#include <math.h>

namespace cg = cooperative_groups;

// Problem constants (from reference)
#define BATCH   2
#define SEQ     512     // N
#define DIN     512
#define DM      256     // d_model

#define LOG2E2  2.88539008177792681f   // 2*log2(e)

#if __has_builtin(__builtin_amdgcn_exp2f)
#define EXP2(x) __builtin_amdgcn_exp2f(x)
#else
#define EXP2(x) exp2f(x)
#endif
#if __has_builtin(__builtin_amdgcn_rcpf)
#define RCP(x) __builtin_amdgcn_rcpf(x)
#else
#define RCP(x) (1.0f / (x))
#endif

// tanh(t) with targ = 2*log2(e)*t: tanh = 1 - 2/(1 + exp2(targ)); overflow-safe.
__device__ __forceinline__ float tanh_from_scaled(float targ) {
    return fmaf(-2.0f, RCP(1.0f + EXP2(targ)), 1.0f);
}

// LDS union layout (phase A: 54272 B; phase B: 41088 B; max < 64 KB static limit)
#define SMEM_BYTES 54272

// ---------------- Fused cooperative kernel ----------------
// 256 blocks x 512 threads, 1 block/CU (co-resident).
// Phase A: every block computes one 32x32 h-tile (k-split halves, r17-verified);
//          blocks [0,128) first write 4 EB d-rows each (r17-verified).
// grid.sync()
// Phase B: r17-verified attend body (EA inline + score 4-row + softmax + AV).
__global__ __launch_bounds__(512) void fused_k(
    const float* __restrict__ pos,   // [B, N, 4]
    const float* __restrict__ Wp,    // [4, DM]
    const float* __restrict__ bp,    // [DM]
    const int*   __restrict__ mask,  // [B, N, N]
    const float* __restrict__ wv,    // [DM]
    const float* __restrict__ x,     // [B*N, DIN]
    const float* __restrict__ Wx,    // [DIN, DM]
    const float* __restrict__ bx,    // [DM]
    float* __restrict__ EBf,         // [B][DM][SEQ] workspace
    float* __restrict__ h,           // [B*N, DM] workspace
    float* __restrict__ out,         // [B, N, DM]
    float* __restrict__ attn_out)    // [B, N, N]
{
    __shared__ __align__(16) char smem[SMEM_BYTES];

    const int tid = threadIdx.x;

    // ================= PHASE A =================
    // ---- A1: EB writer (blocks 0..127), no LDS ----
    if (blockIdx.x < 128) {
        const int b  = blockIdx.x >> 6;
        const int q  = blockIdx.x & 63;
        const int d0 = 4 * q;
        const float4 p = ((const float4*)pos)[b * SEQ + tid];   // coalesced 16B
        #pragma unroll
        for (int i = 0; i < 4; i++) {
            const int d = d0 + i;
            const float P = fmaf(p.x, Wp[d], fmaf(p.y, Wp[DM + d],
                            fmaf(p.z, Wp[2*DM + d], p.w * Wp[3*DM + d])));
            EBf[((size_t)(b * DM + d)) * SEQ + tid] = EXP2(-LOG2E2 * P);  // coalesced
        }
    }

    // ---- A2: h tile 32 rows x 32 cols, k split across thread halves ----
    {
        float (*s_xt)[32][68] = (float(*)[32][68])(smem);            // 17408 B
        float (*s_wt)[64][32] = (float(*)[64][32])(smem + 17408);    // 32768 B
        float4* s_part        = (float4*)(smem + 17408 + 32768);     //  4096 B

        const int idx = blockIdx.x;        // 0..255 -> 32 row-tiles x 8 col-tiles
        const int rt  = idx >> 3;
        const int ct  = idx & 7;
        const int kh  = __builtin_amdgcn_readfirstlane(tid >> 8);    // 0/1 k-half
        const int t   = tid & 255;
        const int ty  = t >> 3;            // 0..31 row in tile
        const int tx  = t & 7;             // 0..7 col quad
        const int row = rt * 32 + ty;

        float4 acc = make_float4(0.f, 0.f, 0.f, 0.f);

        for (int ks = 0; ks < 4; ks++) {
            const int k0 = kh * 256 + ks * 64;
            #pragma unroll
            for (int s = 0; s < 2; s++) {
                const int fidx = t * 2 + s;
                const int r = fidx >> 4, c = fidx & 15;
                *(float4*)&s_xt[kh][r][4 * c] =
                    *(const float4*)(x + (size_t)(rt * 32 + r) * DIN + k0 + 4 * c);
            }
            #pragma unroll
            for (int s = 0; s < 2; s++) {
                const int fidx = t * 2 + s;
                const int r = fidx >> 3, c = fidx & 7;
                *(float4*)&s_wt[kh][r][4 * c] =
                    *(const float4*)(Wx + (size_t)(k0 + r) * DM + ct * 32 + 4 * c);
            }
            __syncthreads();

            #pragma unroll 8
            for (int k = 0; k < 64; k++) {
                const float  xv = s_xt[kh][ty][k];
                const float4 wq = *(const float4*)&s_wt[kh][k][4 * tx];
                acc.x = fmaf(xv, wq.x, acc.x);
                acc.y = fmaf(xv, wq.y, acc.y);
                acc.z = fmaf(xv, wq.z, acc.z);
                acc.w = fmaf(xv, wq.w, acc.w);
            }
            __syncthreads();
        }

        if (kh == 1) s_part[t] = acc;
        __syncthreads();
        if (kh == 0) {
            const float4 q4 = s_part[t];
            const float4 bq = *(const float4*)(bx + ct * 32 + 4 * tx);
            float4 o;
            o.x = tanh_from_scaled(LOG2E2 * (acc.x + q4.x + bq.x));
            o.y = tanh_from_scaled(LOG2E2 * (acc.y + q4.y + bq.y));
            o.z = tanh_from_scaled(LOG2E2 * (acc.z + q4.z + bq.z));
            o.w = tanh_from_scaled(LOG2E2 * (acc.w + q4.w + bq.w));
            *(float4*)(h + (size_t)row * DM + ct * 32 + 4 * tx) = o;
        }
    }

    // ================= GRID BARRIER =================
    cg::this_grid().sync();

    // ================= PHASE B: attend (r17-verified body) =================
    float4* s_ea        = (float4*)(smem);                 //  4096 B
    float (*s_p)[SEQ]   = (float(*)[SEQ])(smem + 4096);    //  8192 B
    float (*s_red)[8]   = (float(*)[8])(smem + 12288);     //   128 B
    float (*s_o)[4][DM] = (float(*)[4][DM])(smem + 12416); // 28672 B

    const int b  = blockIdx.x >> 7;          // 128 blocks per batch
    const int i0 = (blockIdx.x & 127) * 4;   // rows i0..i0+3
    const int l  = tid & 63;

    // ---- EA prologue ----
    {
        const int d  = tid & 255;
        const int rp = __builtin_amdgcn_readfirstlane(tid >> 8);   // 0/1
        const int r0 = rp * 2;
        const float4 p0 = ((const float4*)pos)[b * SEQ + i0 + r0];
        const float4 p1 = ((const float4*)pos)[b * SEQ + i0 + r0 + 1];
        const float wp0 = Wp[d], wp1 = Wp[DM + d], wp2 = Wp[2*DM + d], wp3 = Wp[3*DM + d];
        const float bpd = bp[d];
        const float P0 = fmaf(p0.x, wp0, fmaf(p0.y, wp1, fmaf(p0.z, wp2, p0.w * wp3)));
        const float P1 = fmaf(p1.x, wp0, fmaf(p1.y, wp1, fmaf(p1.z, wp2, p1.w * wp3)));
        float* se = (float*)&s_ea[d];
        se[r0]     = EXP2(LOG2E2 * (P0 + bpd));
        se[r0 + 1] = EXP2(LOG2E2 * (P1 + bpd));
    }
    __syncthreads();

    // ---- score: 128 d-pair iters; pair-merged rcp ----
    const float* __restrict__ EBj = EBf + (size_t)b * DM * SEQ + tid;   // j = tid

    float a0 = 0.f, a1 = 0.f, a2 = 0.f, a3 = 0.f;
    #pragma unroll 8
    for (int t = 0; t < 128; t++) {
        const float eb0 = EBj[(size_t)(2*t) * SEQ];
        const float eb1 = EBj[(size_t)(2*t + 1) * SEQ];
        const float4 eA = s_ea[2*t];
        const float4 eB = s_ea[2*t + 1];
        const float w0 = wv[2*t];
        const float w1 = wv[2*t + 1];

        {
            const float y0 = fmaf(eA.x, eb0, 1.f), y1 = fmaf(eB.x, eb1, 1.f);
            a0 = fmaf(fmaf(w0, y1, w1 * y0), RCP(y0 * y1), a0);
        }
        {
            const float y0 = fmaf(eA.y, eb0, 1.f), y1 = fmaf(eB.y, eb1, 1.f);
            a1 = fmaf(fmaf(w0, y1, w1 * y0), RCP(y0 * y1), a1);
        }
        {
            const float y0 = fmaf(eA.z, eb0, 1.f), y1 = fmaf(eB.z, eb1, 1.f);
            a2 = fmaf(fmaf(w0, y1, w1 * y0), RCP(y0 * y1), a2);
        }
        {
            const float y0 = fmaf(eA.w, eb0, 1.f), y1 = fmaf(eB.w, eb1, 1.f);
            a3 = fmaf(fmaf(w0, y1, w1 * y0), RCP(y0 * y1), a3);
        }
    }

    // ---- masked softmax, 4 rows ----
    const size_t mrow = (size_t)b * SEQ * SEQ + (size_t)i0 * SEQ + tid;
    const int m0 = mask[mrow];
    const int m1 = mask[mrow + SEQ];
    const int m2 = mask[mrow + 2*SEQ];
    const int m3 = mask[mrow + 3*SEQ];
    float p0 = m0 ? EXP2(-LOG2E2 * a0) : 0.f;
    float p1 = m1 ? EXP2(-LOG2E2 * a1) : 0.f;
    float p2 = m2 ? EXP2(-LOG2E2 * a2) : 0.f;
    float p3 = m3 ? EXP2(-LOG2E2 * a3) : 0.f;

    float s0 = p0, s1 = p1, s2 = p2, s3 = p3;
    #pragma unroll
    for (int off = 32; off; off >>= 1) {
        s0 += __shfl_xor(s0, off, 64);
        s1 += __shfl_xor(s1, off, 64);
        s2 += __shfl_xor(s2, off, 64);
        s3 += __shfl_xor(s3, off, 64);
    }
    const int w = tid >> 6;   // 0..7
    if (l == 0) { s_red[0][w] = s0; s_red[1][w] = s1; s_red[2][w] = s2; s_red[3][w] = s3; }
    __syncthreads();

    {
        const float4 r0a = ((const float4*)s_red[0])[0], r0b = ((const float4*)s_red[0])[1];
        const float4 r1a = ((const float4*)s_red[1])[0], r1b = ((const float4*)s_red[1])[1];
        const float4 r2a = ((const float4*)s_red[2])[0], r2b = ((const float4*)s_red[2])[1];
        const float4 r3a = ((const float4*)s_red[3])[0], r3b = ((const float4*)s_red[3])[1];
        p0 *= __fdividef(1.0f, (r0a.x+r0a.y+r0a.z+r0a.w) + (r0b.x+r0b.y+r0b.z+r0b.w));
        p1 *= __fdividef(1.0f, (r1a.x+r1a.y+r1a.z+r1a.w) + (r1b.x+r1b.y+r1b.z+r1b.w));
        p2 *= __fdividef(1.0f, (r2a.x+r2a.y+r2a.z+r2a.w) + (r2b.x+r2b.y+r2b.z+r2b.w));
        p3 *= __fdividef(1.0f, (r3a.x+r3a.y+r3a.z+r3a.w) + (r3b.x+r3b.y+r3b.z+r3b.w));
    }

    attn_out[mrow]         = p0;
    attn_out[mrow + SEQ]   = p1;
    attn_out[mrow + 2*SEQ] = p2;
    attn_out[mrow + 3*SEQ] = p3;
    s_p[0][tid] = p0; s_p[1][tid] = p1; s_p[2][tid] = p2; s_p[3][tid] = p3;
    __syncthreads();

    // ---- av: out[i_r, d] = sum_j p_r[j] * h[b,j,d], 4 rows share h loads ----
    const int dq = tid & 63;
    const int js = __builtin_amdgcn_readfirstlane(tid >> 6);    // 0..7 -> 64-j slice
    const float* __restrict__ hp = h + (size_t)(b * SEQ + js * 64) * DM + 4 * dq;
    const float* __restrict__ q0p = &s_p[0][js * 64];
    const float* __restrict__ q1p = &s_p[1][js * 64];
    const float* __restrict__ q2p = &s_p[2][js * 64];
    const float* __restrict__ q3p = &s_p[3][js * 64];

    float4 a0v = make_float4(0,0,0,0), a1v = a0v, a2v = a0v, a3v = a0v;
    #pragma unroll 4
    for (int jj = 0; jj < 16; jj++) {
        const float4 P0 = *(const float4*)(q0p + 4 * jj);
        const float4 P1 = *(const float4*)(q1p + 4 * jj);
        const float4 P2 = *(const float4*)(q2p + 4 * jj);
        const float4 P3 = *(const float4*)(q3p + 4 * jj);
        const float4 h0 = *(const float4*)(hp + (size_t)(4*jj + 0) * DM);
        const float4 h1 = *(const float4*)(hp + (size_t)(4*jj + 1) * DM);
        const float4 h2 = *(const float4*)(hp + (size_t)(4*jj + 2) * DM);
        const float4 h3 = *(const float4*)(hp + (size_t)(4*jj + 3) * DM);

        a0v.x = fmaf(P0.x,h0.x,fmaf(P0.y,h1.x,fmaf(P0.z,h2.x,fmaf(P0.w,h3.x,a0v.x))));
        a0v.y = fmaf(P0.x,h0.y,fmaf(P0.y,h1.y,fmaf(P0.z,h2.y,fmaf(P0.w,h3.y,a0v.y))));
        a0v.z = fmaf(P0.x,h0.z,fmaf(P0.y,h1.z,fmaf(P0.z,h2.z,fmaf(P0.w,h3.z,a0v.z))));
        a0v.w = fmaf(P0.x,h0.w,fmaf(P0.y,h1.w,fmaf(P0.z,h2.w,fmaf(P0.w,h3.w,a0v.w))));
        a1v.x = fmaf(P1.x,h0.x,fmaf(P1.y,h1.x,fmaf(P1.z,h2.x,fmaf(P1.w,h3.x,a1v.x))));
        a1v.y = fmaf(P1.x,h0.y,fmaf(P1.y,h1.y,fmaf(P1.z,h2.y,fmaf(P1.w,h3.y,a1v.y))));
        a1v.z = fmaf(P1.x,h0.z,fmaf(P1.y,h1.z,fmaf(P1.z,h2.z,fmaf(P1.w,h3.z,a1v.z))));
        a1v.w = fmaf(P1.x,h0.w,fmaf(P1.y,h1.w,fmaf(P1.z,h2.w,fmaf(P1.w,h3.w,a1v.w))));
        a2v.x = fmaf(P2.x,h0.x,fmaf(P2.y,h1.x,fmaf(P2.z,h2.x,fmaf(P2.w,h3.x,a2v.x))));
        a2v.y = fmaf(P2.x,h0.y,fmaf(P2.y,h1.y,fmaf(P2.z,h2.y,fmaf(P2.w,h3.y,a2v.y))));
        a2v.z = fmaf(P2.x,h0.z,fmaf(P2.y,h1.z,fmaf(P2.z,h2.z,fmaf(P2.w,h3.z,a2v.z))));
        a2v.w = fmaf(P2.x,h0.w,fmaf(P2.y,h1.w,fmaf(P2.z,h2.w,fmaf(P2.w,h3.w,a2v.w))));
        a3v.x = fmaf(P3.x,h0.x,fmaf(P3.y,h1.x,fmaf(P3.z,h2.x,fmaf(P3.w,h3.x,a3v.x))));
        a3v.y = fmaf(P3.x,h0.y,fmaf(P3.y,h1.y,fmaf(P3.z,h2.y,fmaf(P3.w,h3.y,a3v.y))));
        a3v.z = fmaf(P3.x,h0.z,fmaf(P3.y,h1.z,fmaf(P3.z,h2.z,fmaf(P3.w,h3.z,a3v.z))));
        a3v.w = fmaf(P3.x,h0.w,fmaf(P3.y,h1.w,fmaf(P3.z,h2.w,fmaf(P3.w,h3.w,a3v.w))));
    }

    if (js > 0) {
        *(float4*)&s_o[js - 1][0][4 * dq] = a0v;
        *(float4*)&s_o[js - 1][1][4 * dq] = a1v;
        *(float4*)&s_o[js - 1][2][4 * dq] = a2v;
        *(float4*)&s_o[js - 1][3][4 * dq] = a3v;
    }
    __syncthreads();
    if (js == 0) {
        #pragma unroll
        for (int s = 0; s < 7; s++) {
            const float4 q0 = *(const float4*)&s_o[s][0][4 * dq];
            const float4 q1 = *(const float4*)&s_o[s][1][4 * dq];
            const float4 q2 = *(const float4*)&s_o[s][2][4 * dq];
            const float4 q3 = *(const float4*)&s_o[s][3][4 * dq];
            a0v.x += q0.x; a0v.y += q0.y; a0v.z += q0.z; a0v.w += q0.w;
            a1v.x += q1.x; a1v.y += q1.y; a1v.z += q1.z; a1v.w += q1.w;
            a2v.x += q2.x; a2v.y += q2.y; a2v.z += q2.z; a2v.w += q2.w;
            a3v.x += q3.x; a3v.y += q3.y; a3v.z += q3.z; a3v.w += q3.w;
        }
        float* __restrict__ op = out + (size_t)(b * SEQ + i0) * DM + 4 * dq;
        *(float4*)(op)        = a0v;
        *(float4*)(op + DM)   = a1v;
        *(float4*)(op + 2*DM) = a2v;
        *(float4*)(op + 3*DM) = a3v;
    }
}

extern "C" void kernel_launch(void* const* d_in, const int* in_sizes, int n_in,
                              void* d_out, int out_size, void* d_ws, size_t ws_size,
                              hipStream_t stream) {
    const float* x    = (const float*)d_in[0];
    const float* pos  = (const float*)d_in[1];
    const int*   mask = (const int*)  d_in[2];
    const float* Wx   = (const float*)d_in[3];
    const float* bx   = (const float*)d_in[4];
    const float* Wp   = (const float*)d_in[5];
    const float* bp   = (const float*)d_in[6];
    const float* wv   = (const float*)d_in[7];

    float* out      = (float*)d_out;                          // [B,N,DM]
    float* attn_out = (float*)d_out + (size_t)BATCH*SEQ*DM;   // [B,N,N]

    char*  ws  = (char*)d_ws;
    float* h   = (float*)(ws);                                // 1 MB
    float* EBf = (float*)(ws + (size_t)BATCH*SEQ*DM*4);       // 1 MB

    void* kargs[] = {
        (void*)&pos, (void*)&Wp, (void*)&bp, (void*)&mask, (void*)&wv,
        (void*)&x, (void*)&Wx, (void*)&bx, (void*)&EBf, (void*)&h,
        (void*)&out, (void*)&attn_out
    };
    hipLaunchCooperativeKernel((const void*)fused_k, dim3(256), dim3(512),
                               kargs, 0, stream);
}

// Round 19
// 106.044 us; speedup vs baseline: 1.4495x; 1.4495x over previous
//
#include <hip/hip_runtime.h>
#include <hip/hip_bf16.h>
#include <math.h>

// Problem constants (from reference)
#define BATCH   2
#define SEQ     512     // N
#define DIN     512
#define DM      256     // d_model

#define LOG2E2  2.88539008177792681f   // 2*log2(e)

#if __has_builtin(__builtin_amdgcn_exp2f)
#define EXP2(x) __builtin_amdgcn_exp2f(x)
#else
#define EXP2(x) exp2f(x)
#endif
#if __has_builtin(__builtin_amdgcn_rcpf)
#define RCP(x) __builtin_amdgcn_rcpf(x)
#else
#define RCP(x) (1.0f / (x))
#endif

// tanh(t) with targ = 2*log2(e)*t: tanh = 1 - 2/(1 + exp2(targ)); overflow-safe.
__device__ __forceinline__ float tanh_from_scaled(float targ) {
    return fmaf(-2.0f, RCP(1.0f + EXP2(targ)), 1.0f);
}

// ---------------- Kernel 1: EB rows + h tiled GEMM (r17-verified, 107.5 us total) ----
// 384 blocks x 512 threads.
//  blocks [0,128):   EBf[(b*256+d)][j] = exp2(-c*P_d(j)), 4 d-rows per block (coalesced)
//  blocks [128,384): h tile 32 rows x 32 cols, k split across thread halves (full 256-CU
//                    coverage), X and Wx LDS-staged, LDS partial combine.
__global__ __launch_bounds__(512) void produce_k(
    const float* __restrict__ pos,  // [B, N, 4]
    const float* __restrict__ Wp,   // [4, DM]
    const float* __restrict__ x,    // [B*N, DIN]
    const float* __restrict__ Wx,   // [DIN, DM]
    const float* __restrict__ bx,   // [DM]
    float* __restrict__ EBf,        // [B][DM][SEQ] floats
    float* __restrict__ h)          // [B*N, DM]
{
    const int tid = threadIdx.x;

    if (blockIdx.x < 128) {
        const int b  = blockIdx.x >> 6;
        const int q  = blockIdx.x & 63;
        const int d0 = 4 * q;
        const float4 p = ((const float4*)pos)[b * SEQ + tid];   // coalesced 16B
        #pragma unroll
        for (int i = 0; i < 4; i++) {
            const int d = d0 + i;
            const float P = fmaf(p.x, Wp[d], fmaf(p.y, Wp[DM + d],
                            fmaf(p.z, Wp[2*DM + d], p.w * Wp[3*DM + d])));
            EBf[((size_t)(b * DM + d)) * SEQ + tid] = EXP2(-LOG2E2 * P);  // coalesced
        }
        return;
    }

    // ---- h tile: 32 rows x 32 cols, k-halves across thread halves ----
    __shared__ float  s_xt[2][32][68];   // 17.4 KB
    __shared__ float  s_wt[2][64][32];   // 32 KB
    __shared__ float4 s_part[256];       // 4 KB

    const int idx = blockIdx.x - 128;  // 0..255
    const int rt  = idx >> 3;          // 0..31 row tile
    const int ct  = idx & 7;           // 0..7 col tile (32 cols)
    const int kh  = __builtin_amdgcn_readfirstlane(tid >> 8);  // 0/1 k-half
    const int t   = tid & 255;
    const int ty  = t >> 3;            // 0..31 row in tile
    const int tx  = t & 7;             // 0..7 col quad
    const int row = rt * 32 + ty;

    float4 acc = make_float4(0.f, 0.f, 0.f, 0.f);

    for (int ks = 0; ks < 4; ks++) {
        const int k0 = kh * 256 + ks * 64;
        // stage X tile for this half: 32 rows x 16 quads = 512 quads, 2/thread
        #pragma unroll
        for (int s = 0; s < 2; s++) {
            const int fidx = t * 2 + s;
            const int r = fidx >> 4, c = fidx & 15;
            *(float4*)&s_xt[kh][r][4 * c] =
                *(const float4*)(x + (size_t)(rt * 32 + r) * DIN + k0 + 4 * c);
        }
        // stage Wx tile: 64 k x 8 quads = 512 quads, 2/thread
        #pragma unroll
        for (int s = 0; s < 2; s++) {
            const int fidx = t * 2 + s;
            const int r = fidx >> 3, c = fidx & 7;
            *(float4*)&s_wt[kh][r][4 * c] =
                *(const float4*)(Wx + (size_t)(k0 + r) * DM + ct * 32 + 4 * c);
        }
        __syncthreads();

        #pragma unroll 8
        for (int k = 0; k < 64; k++) {
            const float  xv = s_xt[kh][ty][k];                       // b32 broadcast-ish
            const float4 wq = *(const float4*)&s_wt[kh][k][4 * tx];  // b128 conflict-free
            acc.x = fmaf(xv, wq.x, acc.x);
            acc.y = fmaf(xv, wq.y, acc.y);
            acc.z = fmaf(xv, wq.z, acc.z);
            acc.w = fmaf(xv, wq.w, acc.w);
        }
        __syncthreads();
    }

    if (kh == 1) s_part[t] = acc;
    __syncthreads();
    if (kh == 0) {
        const float4 q4 = s_part[t];
        const float4 bq = *(const float4*)(bx + ct * 32 + 4 * tx);
        float4 o;
        o.x = tanh_from_scaled(LOG2E2 * (acc.x + q4.x + bq.x));
        o.y = tanh_from_scaled(LOG2E2 * (acc.y + q4.y + bq.y));
        o.z = tanh_from_scaled(LOG2E2 * (acc.z + q4.z + bq.z));
        o.w = tanh_from_scaled(LOG2E2 * (acc.w + q4.w + bq.w));
        *(float4*)(h + (size_t)row * DM + ct * 32 + 4 * tx) = o;
    }
}

// ---------------- Kernel 2: EA (inline) + scores + softmax + AV (r17-verified) --------
// 256 blocks (4 i-rows each) x 512 threads.
// Score: thread = j; 128 d-pair iters; s_ea[d] = {ea_r0..ea_r3} one b128 per d;
// pair-merged rcp (1 rcp per row per d-pair).
__global__ __launch_bounds__(512) void attend_k(
    const float* __restrict__ pos,   // [B, N, 4]
    const float* __restrict__ Wp,    // [4, DM]
    const float* __restrict__ bp,    // [DM]
    const int*   __restrict__ mask,  // [B, N, N]
    const float* __restrict__ wv,    // [DM]
    const float* __restrict__ EBf,   // [B][DM][SEQ]
    const float* __restrict__ h,     // [B, N, DM]
    float* __restrict__ out,         // [B, N, DM]
    float* __restrict__ attn_out)    // [B, N, N]
{
    const int b   = blockIdx.x >> 7;         // 128 blocks per batch
    const int i0  = (blockIdx.x & 127) * 4;  // rows i0..i0+3
    const int tid = threadIdx.x;             // = j in score phase
    const int l   = tid & 63;

    __shared__ float4 s_ea[DM];       // 4 KB: {ea_row0..ea_row3} per d
    __shared__ float  s_p[4][SEQ];    // 8 KB
    __shared__ float  s_red[4][8];
    __shared__ float  s_o[7][4][DM];  // 28 KB

    // ---- EA prologue: thread = (d = tid&255, rp = tid>>8 -> rows {2rp, 2rp+1}) ----
    {
        const int d  = tid & 255;
        const int rp = __builtin_amdgcn_readfirstlane(tid >> 8);   // 0/1
        const int r0 = rp * 2;
        const float4 p0 = ((const float4*)pos)[b * SEQ + i0 + r0];     // uniform s_load
        const float4 p1 = ((const float4*)pos)[b * SEQ + i0 + r0 + 1];
        const float wp0 = Wp[d], wp1 = Wp[DM + d], wp2 = Wp[2*DM + d], wp3 = Wp[3*DM + d];
        const float bpd = bp[d];
        const float P0 = fmaf(p0.x, wp0, fmaf(p0.y, wp1, fmaf(p0.z, wp2, p0.w * wp3)));
        const float P1 = fmaf(p1.x, wp0, fmaf(p1.y, wp1, fmaf(p1.z, wp2, p1.w * wp3)));
        float* se = (float*)&s_ea[d];
        se[r0]     = EXP2(LOG2E2 * (P0 + bpd));
        se[r0 + 1] = EXP2(LOG2E2 * (P1 + bpd));
    }
    __syncthreads();

    // ---- score: 128 d-pair iters; pair-merged rcp ----
    const float* __restrict__ EBj = EBf + (size_t)b * DM * SEQ + tid;   // j = tid

    float a0 = 0.f, a1 = 0.f, a2 = 0.f, a3 = 0.f;
    #pragma unroll 8
    for (int t = 0; t < 128; t++) {
        const float eb0 = EBj[(size_t)(2*t) * SEQ];       // coalesced dword (L2/L3)
        const float eb1 = EBj[(size_t)(2*t + 1) * SEQ];
        const float4 eA = s_ea[2*t];                      // b128 broadcast (4 rows)
        const float4 eB = s_ea[2*t + 1];
        const float w0 = wv[2*t];                         // scalar stream
        const float w1 = wv[2*t + 1];

        // a_r += w0/y0 + w1/y1 = (w0*y1 + w1*y0) * rcp(y0*y1)
        {
            const float y0 = fmaf(eA.x, eb0, 1.f), y1 = fmaf(eB.x, eb1, 1.f);
            a0 = fmaf(fmaf(w0, y1, w1 * y0), RCP(y0 * y1), a0);
        }
        {
            const float y0 = fmaf(eA.y, eb0, 1.f), y1 = fmaf(eB.y, eb1, 1.f);
            a1 = fmaf(fmaf(w0, y1, w1 * y0), RCP(y0 * y1), a1);
        }
        {
            const float y0 = fmaf(eA.z, eb0, 1.f), y1 = fmaf(eB.z, eb1, 1.f);
            a2 = fmaf(fmaf(w0, y1, w1 * y0), RCP(y0 * y1), a2);
        }
        {
            const float y0 = fmaf(eA.w, eb0, 1.f), y1 = fmaf(eB.w, eb1, 1.f);
            a3 = fmaf(fmaf(w0, y1, w1 * y0), RCP(y0 * y1), a3);
        }
    }

    // ---- masked softmax, 4 rows (score = const - 2a; shift-invariant) ----
    const size_t mrow = (size_t)b * SEQ * SEQ + (size_t)i0 * SEQ + tid;
    const int m0 = mask[mrow];
    const int m1 = mask[mrow + SEQ];
    const int m2 = mask[mrow + 2*SEQ];
    const int m3 = mask[mrow + 3*SEQ];
    float p0 = m0 ? EXP2(-LOG2E2 * a0) : 0.f;
    float p1 = m1 ? EXP2(-LOG2E2 * a1) : 0.f;
    float p2 = m2 ? EXP2(-LOG2E2 * a2) : 0.f;
    float p3 = m3 ? EXP2(-LOG2E2 * a3) : 0.f;

    float s0 = p0, s1 = p1, s2 = p2, s3 = p3;
    #pragma unroll
    for (int off = 32; off; off >>= 1) {
        s0 += __shfl_xor(s0, off, 64);
        s1 += __shfl_xor(s1, off, 64);
        s2 += __shfl_xor(s2, off, 64);
        s3 += __shfl_xor(s3, off, 64);
    }
    const int w = tid >> 6;   // 0..7
    if (l == 0) { s_red[0][w] = s0; s_red[1][w] = s1; s_red[2][w] = s2; s_red[3][w] = s3; }
    __syncthreads();

    {
        const float4 r0a = ((const float4*)s_red[0])[0], r0b = ((const float4*)s_red[0])[1];
        const float4 r1a = ((const float4*)s_red[1])[0], r1b = ((const float4*)s_red[1])[1];
        const float4 r2a = ((const float4*)s_red[2])[0], r2b = ((const float4*)s_red[2])[1];
        const float4 r3a = ((const float4*)s_red[3])[0], r3b = ((const float4*)s_red[3])[1];
        p0 *= __fdividef(1.0f, (r0a.x+r0a.y+r0a.z+r0a.w) + (r0b.x+r0b.y+r0b.z+r0b.w));
        p1 *= __fdividef(1.0f, (r1a.x+r1a.y+r1a.z+r1a.w) + (r1b.x+r1b.y+r1b.z+r1b.w));
        p2 *= __fdividef(1.0f, (r2a.x+r2a.y+r2a.z+r2a.w) + (r2b.x+r2b.y+r2b.z+r2b.w));
        p3 *= __fdividef(1.0f, (r3a.x+r3a.y+r3a.z+r3a.w) + (r3b.x+r3b.y+r3b.z+r3b.w));
    }

    attn_out[mrow]         = p0;
    attn_out[mrow + SEQ]   = p1;
    attn_out[mrow + 2*SEQ] = p2;
    attn_out[mrow + 3*SEQ] = p3;
    s_p[0][tid] = p0; s_p[1][tid] = p1; s_p[2][tid] = p2; s_p[3][tid] = p3;
    __syncthreads();

    // ---- av: out[i_r, d] = sum_j p_r[j] * h[b,j,d], 4 rows share h loads ----
    const int dq = tid & 63;                                    // 4-d quad
    const int js = __builtin_amdgcn_readfirstlane(tid >> 6);    // 0..7 -> 64-j slice
    const float* __restrict__ hp = h + (size_t)(b * SEQ + js * 64) * DM + 4 * dq;
    const float* __restrict__ q0p = &s_p[0][js * 64];
    const float* __restrict__ q1p = &s_p[1][js * 64];
    const float* __restrict__ q2p = &s_p[2][js * 64];
    const float* __restrict__ q3p = &s_p[3][js * 64];

    float4 a0v = make_float4(0,0,0,0), a1v = a0v, a2v = a0v, a3v = a0v;
    #pragma unroll 4
    for (int jj = 0; jj < 16; jj++) {
        const float4 P0 = *(const float4*)(q0p + 4 * jj);   // b128 broadcast
        const float4 P1 = *(const float4*)(q1p + 4 * jj);
        const float4 P2 = *(const float4*)(q2p + 4 * jj);
        const float4 P3 = *(const float4*)(q3p + 4 * jj);
        const float4 h0 = *(const float4*)(hp + (size_t)(4*jj + 0) * DM);
        const float4 h1 = *(const float4*)(hp + (size_t)(4*jj + 1) * DM);
        const float4 h2 = *(const float4*)(hp + (size_t)(4*jj + 2) * DM);
        const float4 h3 = *(const float4*)(hp + (size_t)(4*jj + 3) * DM);

        a0v.x = fmaf(P0.x,h0.x,fmaf(P0.y,h1.x,fmaf(P0.z,h2.x,fmaf(P0.w,h3.x,a0v.x))));
        a0v.y = fmaf(P0.x,h0.y,fmaf(P0.y,h1.y,fmaf(P0.z,h2.y,fmaf(P0.w,h3.y,a0v.y))));
        a0v.z = fmaf(P0.x,h0.z,fmaf(P0.y,h1.z,fmaf(P0.z,h2.z,fmaf(P0.w,h3.z,a0v.z))));
        a0v.w = fmaf(P0.x,h0.w,fmaf(P0.y,h1.w,fmaf(P0.z,h2.w,fmaf(P0.w,h3.w,a0v.w))));
        a1v.x = fmaf(P1.x,h0.x,fmaf(P1.y,h1.x,fmaf(P1.z,h2.x,fmaf(P1.w,h3.x,a1v.x))));
        a1v.y = fmaf(P1.x,h0.y,fmaf(P1.y,h1.y,fmaf(P1.z,h2.y,fmaf(P1.w,h3.y,a1v.y))));
        a1v.z = fmaf(P1.x,h0.z,fmaf(P1.y,h1.z,fmaf(P1.z,h2.z,fmaf(P1.w,h3.z,a1v.z))));
        a1v.w = fmaf(P1.x,h0.w,fmaf(P1.y,h1.w,fmaf(P1.z,h2.w,fmaf(P1.w,h3.w,a1v.w))));
        a2v.x = fmaf(P2.x,h0.x,fmaf(P2.y,h1.x,fmaf(P2.z,h2.x,fmaf(P2.w,h3.x,a2v.x))));
        a2v.y = fmaf(P2.x,h0.y,fmaf(P2.y,h1.y,fmaf(P2.z,h2.y,fmaf(P2.w,h3.y,a2v.y))));
        a2v.z = fmaf(P2.x,h0.z,fmaf(P2.y,h1.z,fmaf(P2.z,h2.z,fmaf(P2.w,h3.z,a2v.z))));
        a2v.w = fmaf(P2.x,h0.w,fmaf(P2.y,h1.w,fmaf(P2.z,h2.w,fmaf(P2.w,h3.w,a2v.w))));
        a3v.x = fmaf(P3.x,h0.x,fmaf(P3.y,h1.x,fmaf(P3.z,h2.x,fmaf(P3.w,h3.x,a3v.x))));
        a3v.y = fmaf(P3.x,h0.y,fmaf(P3.y,h1.y,fmaf(P3.z,h2.y,fmaf(P3.w,h3.y,a3v.y))));
        a3v.z = fmaf(P3.x,h0.z,fmaf(P3.y,h1.z,fmaf(P3.z,h2.z,fmaf(P3.w,h3.z,a3v.z))));
        a3v.w = fmaf(P3.x,h0.w,fmaf(P3.y,h1.w,fmaf(P3.z,h2.w,fmaf(P3.w,h3.w,a3v.w))));
    }

    if (js > 0) {
        *(float4*)&s_o[js - 1][0][4 * dq] = a0v;
        *(float4*)&s_o[js - 1][1][4 * dq] = a1v;
        *(float4*)&s_o[js - 1][2][4 * dq] = a2v;
        *(float4*)&s_o[js - 1][3][4 * dq] = a3v;
    }
    __syncthreads();
    if (js == 0) {
        #pragma unroll
        for (int s = 0; s < 7; s++) {
            const float4 q0 = *(const float4*)&s_o[s][0][4 * dq];
            const float4 q1 = *(const float4*)&s_o[s][1][4 * dq];
            const float4 q2 = *(const float4*)&s_o[s][2][4 * dq];
            const float4 q3 = *(const float4*)&s_o[s][3][4 * dq];
            a0v.x += q0.x; a0v.y += q0.y; a0v.z += q0.z; a0v.w += q0.w;
            a1v.x += q1.x; a1v.y += q1.y; a1v.z += q1.z; a1v.w += q1.w;
            a2v.x += q2.x; a2v.y += q2.y; a2v.z += q2.z; a2v.w += q2.w;
            a3v.x += q3.x; a3v.y += q3.y; a3v.z += q3.z; a3v.w += q3.w;
        }
        float* __restrict__ op = out + (size_t)(b * SEQ + i0) * DM + 4 * dq;
        *(float4*)(op)        = a0v;
        *(float4*)(op + DM)   = a1v;
        *(float4*)(op + 2*DM) = a2v;
        *(float4*)(op + 3*DM) = a3v;
    }
}

extern "C" void kernel_launch(void* const* d_in, const int* in_sizes, int n_in,
                              void* d_out, int out_size, void* d_ws, size_t ws_size,
                              hipStream_t stream) {
    const float* x    = (const float*)d_in[0];
    const float* pos  = (const float*)d_in[1];
    const int*   mask = (const int*)  d_in[2];
    const float* Wx   = (const float*)d_in[3];
    const float* bx   = (const float*)d_in[4];
    const float* Wp   = (const float*)d_in[5];
    const float* bp   = (const float*)d_in[6];
    const float* wv   = (const float*)d_in[7];

    float* out      = (float*)d_out;                          // [B,N,DM]
    float* attn_out = (float*)d_out + (size_t)BATCH*SEQ*DM;   // [B,N,N]

    char*  ws  = (char*)d_ws;
    float* h   = (float*)(ws);                                // 1 MB
    float* EBf = (float*)(ws + (size_t)BATCH*SEQ*DM*4);       // 1 MB

    produce_k<<<384, 512, 0, stream>>>(pos, Wp, x, Wx, bx, EBf, h);
    attend_k <<<(BATCH*SEQ)/4, 512, 0, stream>>>(pos, Wp, bp, mask, wv, EBf, h, out, attn_out);
}